// Round 1
// 136.778 us; speedup vs baseline: 1.0002x; 1.0002x over previous
//
#include <hip/hip_runtime.h>
#include <math.h>

typedef _Float16 h2_t __attribute__((ext_vector_type(2)));
typedef _Float16 h4_t __attribute__((ext_vector_type(4)));
typedef _Float16 h8_t __attribute__((ext_vector_type(8)));

#define NP 32
#define KC 31
#define HH 512
#define WW 512
#define BB 4
#define CC 3

#define TXO 64        // 64-wide tile, 512-thread block
#define TYO 32
#define NT 512        // threads per block
#define TROWS 62      // 32 outputs + 15 + 15 halo
#define TWORDS 48     // row stride in h2 words
#define TILEW (TROWS * TWORDS)   // 2976 h2 words per channel tile
#define WSTR 36       // weight table plane stride in h2 words

// HARD CONSTRAINTS (measured, prior session): grid z = BB (channel-split ->
// GB-scale scratch traffic); >128 VGPRs unobtainable -> 4 outputs/thread;
// insert-style unpack (shuffles -20%); fdot2 == pk_fma rate -> inner loop final.
// THIS ROUND: single-dispatch (wtab built per-block in LDS, init kernel deleted),
// all 3 channels staged up-front (loads issued BEFORE the VALU-heavy wtab build
// so HBM latency hides under it), barriers 7 -> 1.

__device__ __forceinline__ double plane_of(int i) {
    const double stepd = 50.0 / 31.0;
    return (i < 31) ? (double)i * stepd : 50.0;
}

__launch_bounds__(512, 2)
__global__ void defocus_kernel(const float* __restrict__ img,
                               const float* __restrict__ coc,
                               float* __restrict__ out) {
    const int tx = threadIdx.x;            // 0..15
    const int ty = threadIdx.y;            // 0..31
    const int tid = ty * 16 + tx;
    const int tilex = blockIdx.x * TXO;
    const int tiley = blockIdx.y * TYO;
    const int b = blockIdx.z;

    __shared__ __align__(16) h2_t wtab[NP * WSTR];          // 4.5 KB
    __shared__ __align__(16) h2_t tile[3 * TILEW];          // 34.9 KB (3 channels)

    const int yo = tiley + ty;
    const int xo = tilex + tx * 4;

    // ---- (1) issue coc load first (feeds the f64 bin search later)
    const float4 cv = *(const float4*)&coc[((size_t)b * HH + yo) * WW + xo];

    // ---- (2) issue ALL THREE channels' staging loads into registers (36 loads
    //          in flight; their latency is hidden under the wtab build below)
    int foff[6]; int fr[6]; bool g0[6], g1[6];
    #pragma unroll
    for (int i = 0; i < 6; ++i) {
        const int f = tid + i * NT;
        const int r = f / TWORDS;
        const int w = f - r * TWORDS;
        const int gy = tiley - 15 + r;
        const int gx = tilex - 15 + 2 * w;
        const bool rowok = (f < TILEW) && ((unsigned)gy < (unsigned)HH);
        g0[i] = rowok && ((unsigned)gx < (unsigned)WW);
        g1[i] = rowok && ((unsigned)(gx + 1) < (unsigned)WW);
        foff[i] = gy * WW + gx;
        fr[i] = f;
    }
    float sv[3][6][2];
    #pragma unroll
    for (int c = 0; c < 3; ++c) {
        const float* src = img + (size_t)(b * CC + c) * HH * WW;
        #pragma unroll
        for (int i = 0; i < 6; ++i) {
            sv[c][i][0] = g0[i] ? src[foff[i]]     : 0.f;
            sv[c][i][1] = g1[i] ? src[foff[i] + 1] : 0.f;
        }
    }

    // ---- (3) per-block weight-table build (bit-identical to old init kernel;
    //          VALU+f64 work that overlaps the outstanding global loads)
    {
        const int t = tid & 31;               // padded tap position 0..31
        #pragma unroll
        for (int pass = 0; pass < 2; ++pass) {
            const int p = (tid >> 5) + 16 * pass;   // plane 0..31
            const double stepd = 50.0 / 31.0;
            double cocp = (p < 31) ? (double)p * stepd : 50.0;  // numpy linspace
            float gt;
            if (cocp < 0.5) {
                gt = (t == 15) ? 1.f : 0.f;   // identity plane (plane 0 only)
            } else {
                double sigma = cocp / 2.355;
                int k = (int)(2.0 * cocp + 1.0);   // trunc, matches python int()
                if ((k & 1) == 0) k += 1;
                if (k > KC) k = KC;
                int h = k / 2;
                int d = t - 15;
                float denom = (float)(2.0 * sigma * sigma);
                float v = (d >= -h && d <= h && t < KC) ? expf(-(float)(d * d) / denom) : 0.f;
                float s = v;
                #pragma unroll
                for (int off = 1; off < 32; off <<= 1) s += __shfl_xor(s, off, 32);
                gt = v / s;
            }
            const int m = t & 15;
            const int s0 = (t < 16) ? (2 * m) : ((2 * m - 1 < 0) ? 0 : 2 * m - 1);
            const int s1 = (t < 16) ? (2 * m + 1) : (2 * m);
            float w0 = __shfl(gt, s0, 32);
            float w1 = __shfl(gt, s1, 32);
            if (t >= 16 && (2 * m - 1) < 0) w0 = 0.f;   // g[-1] = 0
            h2_t w; w.x = (_Float16)w0; w.y = (_Float16)w1;
            wtab[p * WSTR + t] = w;
            if (t < WSTR - 32) {
                h2_t z; z.x = (_Float16)0.f; z.y = (_Float16)0.f;
                wtab[p * WSTR + 32 + t] = z;
            }
        }
    }

    // ---- (4) drain staging loads into the three LDS tiles
    #pragma unroll
    for (int c = 0; c < 3; ++c) {
        #pragma unroll
        for (int i = 0; i < 6; ++i) {
            if (fr[i] < TILEW) {
                h2_t pv; pv.x = (_Float16)sv[c][i][0]; pv.y = (_Float16)sv[c][i][1];
                tile[c * TILEW + fr[i]] = pv;
            }
        }
    }

    // ---- (5) per-pixel bin index, exact double-precision boundary semantics
    const float cocf[4] = {cv.x, cv.y, cv.z, cv.w};
    int idx[4];
    #pragma unroll
    for (int j = 0; j < 4; ++j) {
        const double stepd = 50.0 / 31.0;
        double cd = (double)cocf[j];
        int i0 = (int)floor(cd / stepd + 0.5);
        i0 = min(max(i0, 0), 31);
        if (i0 > 0 && cd <= 0.5 * (plane_of(i0 - 1) + plane_of(i0))) {
            i0 -= 1;
        } else if (i0 < 31 && cd > 0.5 * (plane_of(i0) + plane_of(i0 + 1))) {
            i0 += 1;
        }
        idx[j] = i0;
    }

    __syncthreads();   // the ONLY barrier: wtab + all three tiles are staged

    // ---- (6) gather this thread's 4 weight rows into registers
    // even local col (j=0,2): phase A; odd (j=1,3): phase B (pre-shifted one tap)
    h2_t wj[4][16];
    #pragma unroll
    for (int j = 0; j < 4; ++j) {
        const h2_t* wp = &wtab[idx[j] * WSTR + (j & 1) * 16];
        #pragma unroll
        for (int m = 0; m < 4; ++m) {
            h8_t v = *(const h8_t*)(wp + 4 * m);   // 16B aligned: WSTR%4==0
            #pragma unroll
            for (int q = 0; q < 4; ++q) {
                h2_t t2; t2.x = v[2 * q]; t2.y = v[2 * q + 1];
                wj[j][4 * m + q] = t2;
            }
        }
    }

    // ---- (7) three channel passes back-to-back, no further barriers
    #pragma unroll 1
    for (int c = 0; c < 3; ++c) {
        float acc0 = 0.f, acc1 = 0.f, acc2 = 0.f, acc3 = 0.f;
        const h2_t* rowbase = &tile[c * TILEW + ty * TWORDS + 2 * tx];
        #pragma unroll
        for (int dy = 0; dy < KC; ++dy) {
            const h2_t* rp = rowbase + dy * TWORDS;
            h2_t rw[18];
            #pragma unroll
            for (int m = 0; m < 9; ++m) {
                h4_t q = *(const h4_t*)(rp + 2 * m);   // ds_read_b64, conflict-free
                h2_t lo; lo.x = q[0]; lo.y = q[1];
                h2_t hi; hi.x = q[2]; hi.y = q[3];
                rw[2 * m]     = lo;
                rw[2 * m + 1] = hi;
            }
            float rs0 = 0.f, rs1 = 0.f, rs2 = 0.f, rs3 = 0.f;
            #pragma unroll
            for (int m = 0; m < 16; ++m) {
                rs0 = __builtin_amdgcn_fdot2(wj[0][m], rw[m],     rs0, false);
                rs1 = __builtin_amdgcn_fdot2(wj[1][m], rw[m],     rs1, false);
                rs2 = __builtin_amdgcn_fdot2(wj[2][m], rw[m + 1], rs2, false);
                rs3 = __builtin_amdgcn_fdot2(wj[3][m], rw[m + 1], rs3, false);
            }
            // column taps g[dy] from the same registers (dy unrolled -> static)
            float cw0, cw1, cw2, cw3;
            if ((dy & 1) == 0) {
                cw0 = (float)wj[0][dy >> 1].x;           // A: lo = g[dy]
                cw2 = (float)wj[2][dy >> 1].x;
                cw1 = (float)wj[1][dy >> 1].y;           // B: hi = g[dy]
                cw3 = (float)wj[3][dy >> 1].y;
            } else {
                cw0 = (float)wj[0][dy >> 1].y;           // A: hi = g[dy]
                cw2 = (float)wj[2][dy >> 1].y;
                cw1 = (float)wj[1][(dy + 1) >> 1].x;     // B: lo of next = g[dy]
                cw3 = (float)wj[3][(dy + 1) >> 1].x;
            }
            acc0 += cw0 * rs0;
            acc1 += cw1 * rs1;
            acc2 += cw2 * rs2;
            acc3 += cw3 * rs3;
        }

        *(float4*)&out[((size_t)(b * CC + c) * HH + yo) * WW + xo] =
            make_float4(acc0, acc1, acc2, acc3);
    }
}

extern "C" void kernel_launch(void* const* d_in, const int* in_sizes, int n_in,
                              void* d_out, int out_size, void* d_ws, size_t ws_size,
                              hipStream_t stream) {
    const float* sharp = (const float*)d_in[0];
    const float* cocm  = (const float*)d_in[1];
    float* out = (float*)d_out;

    dim3 grid(WW / TXO, HH / TYO, BB);
    dim3 block(16, 32, 1);
    defocus_kernel<<<grid, block, 0, stream>>>(sharp, cocm, out);
}